// Round 1
// baseline (1636.285 us; speedup 1.0000x reference)
//
#include <hip/hip_runtime.h>
#include <hip/hip_bf16.h>

#define NN 100000
#define NE 3200000
#define NG 1000
#define CH 128
#define OUTC 10
#define BN_EPS 1e-5f

// ---------------- CSR build ----------------
__global__ void count_deg_kernel(const int* __restrict__ dst, int* __restrict__ deg) {
    int e = blockIdx.x * 256 + threadIdx.x;
    if (e < NE) atomicAdd(&deg[dst[e]], 1);
}

__global__ void scan_kernel(const int* __restrict__ deg, int* __restrict__ offs,
                            int* __restrict__ cursor) {
    __shared__ int wsum[16];
    __shared__ int lcarry;
    int t = threadIdx.x;            // 1024 threads
    int lane = t & 63, w = t >> 6;
    if (t == 0) lcarry = 0;
    __syncthreads();
    for (int base = 0; base < NN; base += 1024) {
        int i = base + t;
        int v = (i < NN) ? deg[i] : 0;
        int incl = v;
        #pragma unroll
        for (int d = 1; d < 64; d <<= 1) {
            int u = __shfl_up(incl, d, 64);
            if (lane >= d) incl += u;
        }
        if (lane == 63) wsum[w] = incl;
        __syncthreads();
        if (w == 0) {
            int s = (lane < 16) ? wsum[lane] : 0;
            #pragma unroll
            for (int d = 1; d < 16; d <<= 1) {
                int u = __shfl_up(s, d, 64);
                if (lane >= d) s += u;
            }
            if (lane < 16) wsum[lane] = s;   // inclusive wave sums
        }
        __syncthreads();
        int woff = (w == 0) ? 0 : wsum[w - 1];
        int excl = lcarry + woff + incl - v;
        if (i < NN) { offs[i] = excl; cursor[i] = excl; }
        __syncthreads();
        if (t == 0) lcarry += wsum[15];
        __syncthreads();
    }
}

__global__ void fill_kernel(const int* __restrict__ src, const int* __restrict__ dst,
                            int* __restrict__ cursor, int* __restrict__ csrc) {
    int e = blockIdx.x * 256 + threadIdx.x;
    if (e < NE) {
        int p = atomicAdd(&cursor[dst[e]], 1);
        csrc[p] = src[e];
    }
}

// ---------------- aggregation: out[i] = x[i] + sum_{j in CSR row i} x[j] ----------------
__global__ __launch_bounds__(256) void aggregate_kernel(const float* __restrict__ x,
        const int* __restrict__ offs, const int* __restrict__ deg,
        const int* __restrict__ csrc, float* __restrict__ out) {
    int node = blockIdx.x * 4 + (threadIdx.x >> 6);
    int lane = threadIdx.x & 63;
    const float2* x2 = (const float2*)x;
    float2 acc = x2[(size_t)node * 64 + lane];
    int s = offs[node], d = deg[node];
    for (int e = 0; e < d; ++e) {
        int sv = csrc[s + e];
        float2 v = x2[(size_t)sv * 64 + lane];
        acc.x += v.x; acc.y += v.y;
    }
    ((float2*)out)[(size_t)node * 64 + lane] = acc;
}

// ---------------- f32 GEMM: C = [relu](A[M,128] @ W[128,128] + b) ----------------
template<int RELU>
__global__ __launch_bounds__(256, 2) void gemm128_kernel(const float* __restrict__ A,
        const float* __restrict__ W, const float* __restrict__ bias,
        float* __restrict__ Cout, int M) {
    __shared__ float As[64][132];
    __shared__ float Ws[128][64];
    int t = threadIdx.x;
    int bm = blockIdx.x, bn = blockIdx.y;
    int row0 = bm * 64;
    {
        const float4* A4 = (const float4*)A;
        #pragma unroll
        for (int i = 0; i < 8; ++i) {
            int idx = i * 256 + t;
            int r = idx >> 5, c4 = idx & 31;
            int gr = row0 + r;
            float4 v = (gr < M) ? A4[(size_t)gr * 32 + c4] : make_float4(0.f, 0.f, 0.f, 0.f);
            *(float4*)&As[r][c4 * 4] = v;
        }
        const float4* W4 = (const float4*)W;
        #pragma unroll
        for (int i = 0; i < 8; ++i) {
            int idx = i * 256 + t;
            int k = idx >> 4, c4 = idx & 15;
            float4 v = W4[(size_t)k * 32 + bn * 16 + c4];
            *(float4*)&Ws[k][c4 * 4] = v;
        }
    }
    __syncthreads();
    int tc = t & 15, tr = t >> 4;
    int c0 = tc * 4;
    float acc[4][4] = {};
    for (int k = 0; k < 128; k += 4) {
        float4 a[4], w[4];
        #pragma unroll
        for (int j = 0; j < 4; ++j) a[j] = *(const float4*)&As[tr * 4 + j][k];
        #pragma unroll
        for (int kk = 0; kk < 4; ++kk) w[kk] = *(const float4*)&Ws[k + kk][c0];
        #pragma unroll
        for (int j = 0; j < 4; ++j) {
            float av[4] = {a[j].x, a[j].y, a[j].z, a[j].w};
            #pragma unroll
            for (int kk = 0; kk < 4; ++kk) {
                acc[j][0] += av[kk] * w[kk].x;
                acc[j][1] += av[kk] * w[kk].y;
                acc[j][2] += av[kk] * w[kk].z;
                acc[j][3] += av[kk] * w[kk].w;
            }
        }
    }
    float4 b4 = *(const float4*)&bias[bn * 64 + c0];
    #pragma unroll
    for (int j = 0; j < 4; ++j) {
        int gr = row0 + tr * 4 + j;
        if (gr < M) {
            float4 v = make_float4(acc[j][0] + b4.x, acc[j][1] + b4.y,
                                   acc[j][2] + b4.z, acc[j][3] + b4.w);
            if (RELU) {
                v.x = fmaxf(v.x, 0.f); v.y = fmaxf(v.y, 0.f);
                v.z = fmaxf(v.z, 0.f); v.w = fmaxf(v.w, 0.f);
            }
            *(float4*)&Cout[(size_t)gr * 128 + bn * 64 + c0] = v;
        }
    }
}

// ---------------- BN stats: per-channel sum & sumsq ----------------
__global__ void bn_stats_kernel(const float* __restrict__ U, float* __restrict__ stats) {
    int tid = blockIdx.x * 256 + threadIdx.x;
    int chn = tid & 127;
    float s = 0.f, sq = 0.f;
    const int total = NN * CH;
    for (int i = tid; i < total; i += 2048 * 256) {
        float v = U[i];
        s += v; sq += v * v;
    }
    atomicAdd(&stats[chn], s);
    atomicAdd(&stats[128 + chn], sq);
}

__global__ void bn_relu_kernel(const float* __restrict__ U, const float* __restrict__ stats,
        const float* __restrict__ gamma, const float* __restrict__ beta,
        float* __restrict__ out) {
    int tid = blockIdx.x * 256 + threadIdx.x;   // one float4 each; grid exact
    int c4 = tid & 31;
    float4 u  = ((const float4*)U)[tid];
    float4 sm = ((const float4*)stats)[c4];
    float4 sq = ((const float4*)(stats + 128))[c4];
    float4 g  = ((const float4*)gamma)[c4];
    float4 be = ((const float4*)beta)[c4];
    const float inv = 1.0f / NN;
    float4 o;
    {
        float mean = sm.x * inv, var = sq.x * inv - mean * mean;
        o.x = fmaxf((u.x - mean) * rsqrtf(var + BN_EPS) * g.x + be.x, 0.f);
    }
    {
        float mean = sm.y * inv, var = sq.y * inv - mean * mean;
        o.y = fmaxf((u.y - mean) * rsqrtf(var + BN_EPS) * g.y + be.y, 0.f);
    }
    {
        float mean = sm.z * inv, var = sq.z * inv - mean * mean;
        o.z = fmaxf((u.z - mean) * rsqrtf(var + BN_EPS) * g.z + be.z, 0.f);
    }
    {
        float mean = sm.w * inv, var = sq.w * inv - mean * mean;
        o.w = fmaxf((u.w - mean) * rsqrtf(var + BN_EPS) * g.w + be.w, 0.f);
    }
    ((float4*)out)[tid] = o;
}

// ---------------- pooling: segment_sum over sorted batch ----------------
__global__ void pool_kernel(const float* __restrict__ h, const int* __restrict__ batch,
                            float* __restrict__ pooled) {
    int g = blockIdx.x;
    int t = threadIdx.x;   // 128
    int a = 0, b = NN;
    while (a < b) { int m = (a + b) >> 1; if (batch[m] < g) a = m + 1; else b = m; }
    int start = a;
    b = NN;
    while (a < b) { int m = (a + b) >> 1; if (batch[m] < g + 1) a = m + 1; else b = m; }
    int end = a;
    float s = 0.f;
    for (int i = start; i < end; ++i) s += h[(size_t)i * 128 + t];
    pooled[g * 128 + t] = s;
}

// ---------------- head: logits + log_softmax ----------------
__global__ void head_kernel(const float* __restrict__ pooled, const float* __restrict__ Wlin,
                            const float* __restrict__ blin, float* __restrict__ out) {
    int g = blockIdx.x;
    int lane = threadIdx.x;  // 64
    float2 p = ((const float2*)pooled)[g * 64 + lane];
    float l[10];
    #pragma unroll
    for (int o = 0; o < 10; ++o) {
        float partial = p.x * Wlin[(2 * lane) * 10 + o] + p.y * Wlin[(2 * lane + 1) * 10 + o];
        #pragma unroll
        for (int m = 1; m < 64; m <<= 1) partial += __shfl_xor(partial, m, 64);
        l[o] = partial + blin[o];
    }
    float mx = l[0];
    #pragma unroll
    for (int o = 1; o < 10; ++o) mx = fmaxf(mx, l[o]);
    float se = 0.f;
    #pragma unroll
    for (int o = 0; o < 10; ++o) se += expf(l[o] - mx);
    float lse = mx + logf(se);
    if (lane == 0) {
        #pragma unroll
        for (int o = 0; o < 10; ++o) out[g * 10 + o] = l[o] - lse;
    }
}

extern "C" void kernel_launch(void* const* d_in, const int* in_sizes, int n_in,
                              void* d_out, int out_size, void* d_ws, size_t ws_size,
                              hipStream_t stream) {
    const float* x    = (const float*)d_in[0];
    const int*   edge = (const int*)d_in[1];   // [2][NE]
    const int*   batch= (const int*)d_in[2];
    const float* W1a  = (const float*)d_in[3];
    const float* b1a  = (const float*)d_in[4];
    const float* W1b  = (const float*)d_in[5];
    const float* b1b  = (const float*)d_in[6];
    const float* g1   = (const float*)d_in[7];
    const float* be1  = (const float*)d_in[8];
    const float* W2a  = (const float*)d_in[9];
    const float* b2a  = (const float*)d_in[10];
    const float* W2b  = (const float*)d_in[11];
    const float* b2b  = (const float*)d_in[12];
    const float* g2   = (const float*)d_in[13];
    const float* be2  = (const float*)d_in[14];
    const float* Wlin = (const float*)d_in[15];
    const float* blin = (const float*)d_in[16];
    float* out = (float*)d_out;

    char* ws = (char*)d_ws;
    size_t off = 0;
    auto alloc = [&](size_t bytes) -> void* {
        void* p = ws + off; off += (bytes + 255) & ~(size_t)255; return p;
    };
    float* bufA   = (float*)alloc((size_t)NN * CH * 4);
    float* bufB   = (float*)alloc((size_t)NN * CH * 4);
    int*   csrc   = (int*)alloc((size_t)NE * 4);
    int*   offs   = (int*)alloc(NN * 4);
    int*   deg    = (int*)alloc(NN * 4);
    int*   cursor = (int*)alloc(NN * 4);
    float* stats1 = (float*)alloc(256 * 4);
    float* stats2 = (float*)alloc(256 * 4);
    float* pooled = (float*)alloc(NG * CH * 4);

    const int* srcI = edge;
    const int* dstI = edge + NE;

    hipMemsetAsync(deg, 0, NN * 4, stream);
    hipMemsetAsync(stats1, 0, 256 * 4, stream);
    hipMemsetAsync(stats2, 0, 256 * 4, stream);

    count_deg_kernel<<<NE / 256, 256, 0, stream>>>(dstI, deg);
    scan_kernel<<<1, 1024, 0, stream>>>(deg, offs, cursor);
    fill_kernel<<<NE / 256, 256, 0, stream>>>(srcI, dstI, cursor, csrc);

    dim3 ggrid(1563, 2);
    // ---- layer 1 ----
    aggregate_kernel<<<NN / 4, 256, 0, stream>>>(x, offs, deg, csrc, bufA);
    gemm128_kernel<1><<<ggrid, 256, 0, stream>>>(bufA, W1a, b1a, bufB, NN);
    gemm128_kernel<0><<<ggrid, 256, 0, stream>>>(bufB, W1b, b1b, bufA, NN);
    bn_stats_kernel<<<2048, 256, 0, stream>>>(bufA, stats1);
    bn_relu_kernel<<<12500, 256, 0, stream>>>(bufA, stats1, g1, be1, bufA);
    // ---- layer 2 ----
    aggregate_kernel<<<NN / 4, 256, 0, stream>>>(bufA, offs, deg, csrc, bufB);
    gemm128_kernel<1><<<ggrid, 256, 0, stream>>>(bufB, W2a, b2a, bufA, NN);
    gemm128_kernel<0><<<ggrid, 256, 0, stream>>>(bufA, W2b, b2b, bufB, NN);
    bn_stats_kernel<<<2048, 256, 0, stream>>>(bufB, stats2);
    bn_relu_kernel<<<12500, 256, 0, stream>>>(bufB, stats2, g2, be2, bufB);

    pool_kernel<<<NG, 128, 0, stream>>>(bufB, batch, pooled);
    head_kernel<<<NG, 64, 0, stream>>>(pooled, Wlin, blin, out);
}

// Round 2
// 1471.777 us; speedup vs baseline: 1.1118x; 1.1118x over previous
//
#include <hip/hip_runtime.h>
#include <hip/hip_bf16.h>

#define NN 100000
#define NE 3200000
#define NG 1000
#define CH 128
#define OUTC 10
#define BN_EPS 1e-5f

// ---------------- CSR build ----------------
__global__ void count_deg_kernel(const int* __restrict__ dst, int* __restrict__ deg) {
    int e = blockIdx.x * 256 + threadIdx.x;
    if (e < NE) atomicAdd(&deg[dst[e]], 1);
}

__global__ void scan_kernel(const int* __restrict__ deg, int* __restrict__ offs,
                            int* __restrict__ cursor) {
    __shared__ int wsum[16];
    __shared__ int lcarry;
    int t = threadIdx.x;            // 1024 threads
    int lane = t & 63, w = t >> 6;
    if (t == 0) lcarry = 0;
    __syncthreads();
    for (int base = 0; base < NN; base += 1024) {
        int i = base + t;
        int v = (i < NN) ? deg[i] : 0;
        int incl = v;
        #pragma unroll
        for (int d = 1; d < 64; d <<= 1) {
            int u = __shfl_up(incl, d, 64);
            if (lane >= d) incl += u;
        }
        if (lane == 63) wsum[w] = incl;
        __syncthreads();
        if (w == 0) {
            int s = (lane < 16) ? wsum[lane] : 0;
            #pragma unroll
            for (int d = 1; d < 16; d <<= 1) {
                int u = __shfl_up(s, d, 64);
                if (lane >= d) s += u;
            }
            if (lane < 16) wsum[lane] = s;   // inclusive wave sums
        }
        __syncthreads();
        int woff = (w == 0) ? 0 : wsum[w - 1];
        int excl = lcarry + woff + incl - v;
        if (i < NN) { offs[i] = excl; cursor[i] = excl; }
        __syncthreads();
        if (t == 0) lcarry += wsum[15];
        __syncthreads();
    }
}

__global__ void fill_kernel(const int* __restrict__ src, const int* __restrict__ dst,
                            int* __restrict__ cursor, int* __restrict__ csrc) {
    int e = blockIdx.x * 256 + threadIdx.x;
    if (e < NE) {
        int p = atomicAdd(&cursor[dst[e]], 1);
        csrc[p] = src[e];
    }
}

// ---------------- aggregation: out[i] = x[i] + sum_{j in CSR row i} x[j] ----------------
// ILP version: wave-uniform node (readfirstlane -> s_load for indices),
// 8 independent 512B gathers in flight per wave.
__global__ __launch_bounds__(256) void aggregate_kernel(const float* __restrict__ x,
        const int* __restrict__ offs, const int* __restrict__ deg,
        const int* __restrict__ csrc, float* __restrict__ out) {
    int node = __builtin_amdgcn_readfirstlane(blockIdx.x * 4 + (threadIdx.x >> 6));
    int lane = threadIdx.x & 63;
    const float2* x2 = (const float2*)x;
    float2 acc = x2[(size_t)node * 64 + lane];
    int s = offs[node], d = deg[node];
    int i = 0;
    for (; i + 8 <= d; i += 8) {
        int i0 = csrc[s + i + 0];
        int i1 = csrc[s + i + 1];
        int i2 = csrc[s + i + 2];
        int i3 = csrc[s + i + 3];
        int i4 = csrc[s + i + 4];
        int i5 = csrc[s + i + 5];
        int i6 = csrc[s + i + 6];
        int i7 = csrc[s + i + 7];
        float2 v0 = x2[(size_t)i0 * 64 + lane];
        float2 v1 = x2[(size_t)i1 * 64 + lane];
        float2 v2 = x2[(size_t)i2 * 64 + lane];
        float2 v3 = x2[(size_t)i3 * 64 + lane];
        float2 v4 = x2[(size_t)i4 * 64 + lane];
        float2 v5 = x2[(size_t)i5 * 64 + lane];
        float2 v6 = x2[(size_t)i6 * 64 + lane];
        float2 v7 = x2[(size_t)i7 * 64 + lane];
        acc.x += v0.x; acc.y += v0.y;
        acc.x += v1.x; acc.y += v1.y;
        acc.x += v2.x; acc.y += v2.y;
        acc.x += v3.x; acc.y += v3.y;
        acc.x += v4.x; acc.y += v4.y;
        acc.x += v5.x; acc.y += v5.y;
        acc.x += v6.x; acc.y += v6.y;
        acc.x += v7.x; acc.y += v7.y;
    }
    for (; i < d; ++i) {
        int sv = csrc[s + i];
        float2 v = x2[(size_t)sv * 64 + lane];
        acc.x += v.x; acc.y += v.y;
    }
    ((float2*)out)[(size_t)node * 64 + lane] = acc;
}

// ---------------- f32 GEMM: C = [relu](A[M,128] @ W[128,128] + b) ----------------
template<int RELU>
__global__ __launch_bounds__(256, 2) void gemm128_kernel(const float* __restrict__ A,
        const float* __restrict__ W, const float* __restrict__ bias,
        float* __restrict__ Cout, int M) {
    __shared__ float As[64][132];
    __shared__ float Ws[128][64];
    int t = threadIdx.x;
    int bm = blockIdx.x, bn = blockIdx.y;
    int row0 = bm * 64;
    {
        const float4* A4 = (const float4*)A;
        #pragma unroll
        for (int i = 0; i < 8; ++i) {
            int idx = i * 256 + t;
            int r = idx >> 5, c4 = idx & 31;
            int gr = row0 + r;
            float4 v = (gr < M) ? A4[(size_t)gr * 32 + c4] : make_float4(0.f, 0.f, 0.f, 0.f);
            *(float4*)&As[r][c4 * 4] = v;
        }
        const float4* W4 = (const float4*)W;
        #pragma unroll
        for (int i = 0; i < 8; ++i) {
            int idx = i * 256 + t;
            int k = idx >> 4, c4 = idx & 15;
            float4 v = W4[(size_t)k * 32 + bn * 16 + c4];
            *(float4*)&Ws[k][c4 * 4] = v;
        }
    }
    __syncthreads();
    int tc = t & 15, tr = t >> 4;
    int c0 = tc * 4;
    float acc[4][4] = {};
    for (int k = 0; k < 128; k += 4) {
        float4 a[4], w[4];
        #pragma unroll
        for (int j = 0; j < 4; ++j) a[j] = *(const float4*)&As[tr * 4 + j][k];
        #pragma unroll
        for (int kk = 0; kk < 4; ++kk) w[kk] = *(const float4*)&Ws[k + kk][c0];
        #pragma unroll
        for (int j = 0; j < 4; ++j) {
            float av[4] = {a[j].x, a[j].y, a[j].z, a[j].w};
            #pragma unroll
            for (int kk = 0; kk < 4; ++kk) {
                acc[j][0] += av[kk] * w[kk].x;
                acc[j][1] += av[kk] * w[kk].y;
                acc[j][2] += av[kk] * w[kk].z;
                acc[j][3] += av[kk] * w[kk].w;
            }
        }
    }
    float4 b4 = *(const float4*)&bias[bn * 64 + c0];
    #pragma unroll
    for (int j = 0; j < 4; ++j) {
        int gr = row0 + tr * 4 + j;
        if (gr < M) {
            float4 v = make_float4(acc[j][0] + b4.x, acc[j][1] + b4.y,
                                   acc[j][2] + b4.z, acc[j][3] + b4.w);
            if (RELU) {
                v.x = fmaxf(v.x, 0.f); v.y = fmaxf(v.y, 0.f);
                v.z = fmaxf(v.z, 0.f); v.w = fmaxf(v.w, 0.f);
            }
            *(float4*)&Cout[(size_t)gr * 128 + bn * 64 + c0] = v;
        }
    }
}

// ---------------- BN stats: per-channel sum & sumsq ----------------
__global__ void bn_stats_kernel(const float* __restrict__ U, float* __restrict__ stats) {
    int tid = blockIdx.x * 256 + threadIdx.x;
    int chn = tid & 127;
    float s = 0.f, sq = 0.f;
    const int total = NN * CH;
    for (int i = tid; i < total; i += 2048 * 256) {
        float v = U[i];
        s += v; sq += v * v;
    }
    atomicAdd(&stats[chn], s);
    atomicAdd(&stats[128 + chn], sq);
}

__global__ void bn_relu_kernel(const float* __restrict__ U, const float* __restrict__ stats,
        const float* __restrict__ gamma, const float* __restrict__ beta,
        float* __restrict__ out) {
    int tid = blockIdx.x * 256 + threadIdx.x;   // one float4 each; grid exact
    int c4 = tid & 31;
    float4 u  = ((const float4*)U)[tid];
    float4 sm = ((const float4*)stats)[c4];
    float4 sq = ((const float4*)(stats + 128))[c4];
    float4 g  = ((const float4*)gamma)[c4];
    float4 be = ((const float4*)beta)[c4];
    const float inv = 1.0f / NN;
    float4 o;
    {
        float mean = sm.x * inv, var = sq.x * inv - mean * mean;
        o.x = fmaxf((u.x - mean) * rsqrtf(var + BN_EPS) * g.x + be.x, 0.f);
    }
    {
        float mean = sm.y * inv, var = sq.y * inv - mean * mean;
        o.y = fmaxf((u.y - mean) * rsqrtf(var + BN_EPS) * g.y + be.y, 0.f);
    }
    {
        float mean = sm.z * inv, var = sq.z * inv - mean * mean;
        o.z = fmaxf((u.z - mean) * rsqrtf(var + BN_EPS) * g.z + be.z, 0.f);
    }
    {
        float mean = sm.w * inv, var = sq.w * inv - mean * mean;
        o.w = fmaxf((u.w - mean) * rsqrtf(var + BN_EPS) * g.w + be.w, 0.f);
    }
    ((float4*)out)[tid] = o;
}

// ---------------- pooling: segment_sum over sorted batch ----------------
__global__ void pool_kernel(const float* __restrict__ h, const int* __restrict__ batch,
                            float* __restrict__ pooled) {
    int g = blockIdx.x;
    int t = threadIdx.x;   // 128
    int a = 0, b = NN;
    while (a < b) { int m = (a + b) >> 1; if (batch[m] < g) a = m + 1; else b = m; }
    int start = a;
    b = NN;
    while (a < b) { int m = (a + b) >> 1; if (batch[m] < g + 1) a = m + 1; else b = m; }
    int end = a;
    float s = 0.f;
    for (int i = start; i < end; ++i) s += h[(size_t)i * 128 + t];
    pooled[g * 128 + t] = s;
}

// ---------------- head: logits + log_softmax ----------------
__global__ void head_kernel(const float* __restrict__ pooled, const float* __restrict__ Wlin,
                            const float* __restrict__ blin, float* __restrict__ out) {
    int g = blockIdx.x;
    int lane = threadIdx.x;  // 64
    float2 p = ((const float2*)pooled)[g * 64 + lane];
    float l[10];
    #pragma unroll
    for (int o = 0; o < 10; ++o) {
        float partial = p.x * Wlin[(2 * lane) * 10 + o] + p.y * Wlin[(2 * lane + 1) * 10 + o];
        #pragma unroll
        for (int m = 1; m < 64; m <<= 1) partial += __shfl_xor(partial, m, 64);
        l[o] = partial + blin[o];
    }
    float mx = l[0];
    #pragma unroll
    for (int o = 1; o < 10; ++o) mx = fmaxf(mx, l[o]);
    float se = 0.f;
    #pragma unroll
    for (int o = 0; o < 10; ++o) se += expf(l[o] - mx);
    float lse = mx + logf(se);
    if (lane == 0) {
        #pragma unroll
        for (int o = 0; o < 10; ++o) out[g * 10 + o] = l[o] - lse;
    }
}

extern "C" void kernel_launch(void* const* d_in, const int* in_sizes, int n_in,
                              void* d_out, int out_size, void* d_ws, size_t ws_size,
                              hipStream_t stream) {
    const float* x    = (const float*)d_in[0];
    const int*   edge = (const int*)d_in[1];   // [2][NE]
    const int*   batch= (const int*)d_in[2];
    const float* W1a  = (const float*)d_in[3];
    const float* b1a  = (const float*)d_in[4];
    const float* W1b  = (const float*)d_in[5];
    const float* b1b  = (const float*)d_in[6];
    const float* g1   = (const float*)d_in[7];
    const float* be1  = (const float*)d_in[8];
    const float* W2a  = (const float*)d_in[9];
    const float* b2a  = (const float*)d_in[10];
    const float* W2b  = (const float*)d_in[11];
    const float* b2b  = (const float*)d_in[12];
    const float* g2   = (const float*)d_in[13];
    const float* be2  = (const float*)d_in[14];
    const float* Wlin = (const float*)d_in[15];
    const float* blin = (const float*)d_in[16];
    float* out = (float*)d_out;

    char* ws = (char*)d_ws;
    size_t off = 0;
    auto alloc = [&](size_t bytes) -> void* {
        void* p = ws + off; off += (bytes + 255) & ~(size_t)255; return p;
    };
    float* bufA   = (float*)alloc((size_t)NN * CH * 4);
    float* bufB   = (float*)alloc((size_t)NN * CH * 4);
    int*   csrc   = (int*)alloc((size_t)NE * 4);
    int*   offs   = (int*)alloc(NN * 4);
    int*   deg    = (int*)alloc(NN * 4);
    int*   cursor = (int*)alloc(NN * 4);
    float* stats1 = (float*)alloc(256 * 4);
    float* stats2 = (float*)alloc(256 * 4);
    float* pooled = (float*)alloc(NG * CH * 4);

    const int* srcI = edge;
    const int* dstI = edge + NE;

    hipMemsetAsync(deg, 0, NN * 4, stream);
    hipMemsetAsync(stats1, 0, 256 * 4, stream);
    hipMemsetAsync(stats2, 0, 256 * 4, stream);

    count_deg_kernel<<<NE / 256, 256, 0, stream>>>(dstI, deg);
    scan_kernel<<<1, 1024, 0, stream>>>(deg, offs, cursor);
    fill_kernel<<<NE / 256, 256, 0, stream>>>(srcI, dstI, cursor, csrc);

    dim3 ggrid(1563, 2);
    // ---- layer 1 ----
    aggregate_kernel<<<NN / 4, 256, 0, stream>>>(x, offs, deg, csrc, bufA);
    gemm128_kernel<1><<<ggrid, 256, 0, stream>>>(bufA, W1a, b1a, bufB, NN);
    gemm128_kernel<0><<<ggrid, 256, 0, stream>>>(bufB, W1b, b1b, bufA, NN);
    bn_stats_kernel<<<2048, 256, 0, stream>>>(bufA, stats1);
    bn_relu_kernel<<<12500, 256, 0, stream>>>(bufA, stats1, g1, be1, bufA);
    // ---- layer 2 ----
    aggregate_kernel<<<NN / 4, 256, 0, stream>>>(bufA, offs, deg, csrc, bufB);
    gemm128_kernel<1><<<ggrid, 256, 0, stream>>>(bufB, W2a, b2a, bufA, NN);
    gemm128_kernel<0><<<ggrid, 256, 0, stream>>>(bufA, W2b, b2b, bufB, NN);
    bn_stats_kernel<<<2048, 256, 0, stream>>>(bufB, stats2);
    bn_relu_kernel<<<12500, 256, 0, stream>>>(bufB, stats2, g2, be2, bufB);

    pool_kernel<<<NG, 128, 0, stream>>>(bufB, batch, pooled);
    head_kernel<<<NG, 64, 0, stream>>>(pooled, Wlin, blin, out);
}

// Round 3
// 1210.093 us; speedup vs baseline: 1.3522x; 1.2163x over previous
//
#include <hip/hip_runtime.h>
#include <hip/hip_bf16.h>

#define NN 100000
#define NE 3200000
#define NG 1000
#define CH 128
#define OUTC 10
#define BN_EPS 1e-5f

#define BKT_SH 7            // 128 nodes per bucket
#define NBKT 782            // ceil(NN/128)
#define CHUNK 8192          // edges per bin_kernel block
#define NBINBLK 391         // ceil(NE/CHUNK)
#define MAXB 6144           // max entries per bucket (lambda=4096, sigma=64)

// ---------------- bucket histogram ----------------
__global__ __launch_bounds__(256) void bucket_count_kernel(const int* __restrict__ dst,
                                                           int* __restrict__ bcnt) {
    __shared__ int h[NBKT];
    int t = threadIdx.x;
    for (int i = t; i < NBKT; i += 256) h[i] = 0;
    __syncthreads();
    int gid = blockIdx.x * 256 + t;
    for (int e = gid; e < NE; e += NBINBLK * 256) atomicAdd(&h[dst[e] >> BKT_SH], 1);
    __syncthreads();
    for (int i = t; i < NBKT; i += 256) if (h[i]) atomicAdd(&bcnt[i], h[i]);
}

// ---------------- exclusive scan of 782 bucket counts ----------------
__global__ void bucket_scan_kernel(const int* __restrict__ bcnt, int* __restrict__ bbase,
                                   int* __restrict__ bcur) {
    __shared__ int wsum[16];
    int t = threadIdx.x;              // 1024 threads
    int lane = t & 63, w = t >> 6;
    int v = (t < NBKT) ? bcnt[t] : 0;
    int incl = v;
    #pragma unroll
    for (int d = 1; d < 64; d <<= 1) {
        int u = __shfl_up(incl, d, 64);
        if (lane >= d) incl += u;
    }
    if (lane == 63) wsum[w] = incl;
    __syncthreads();
    if (w == 0) {
        int s = (lane < 16) ? wsum[lane] : 0;
        #pragma unroll
        for (int d = 1; d < 16; d <<= 1) {
            int u = __shfl_up(s, d, 64);
            if (lane >= d) s += u;
        }
        if (lane < 16) wsum[lane] = s;
    }
    __syncthreads();
    int excl = (w ? wsum[w - 1] : 0) + incl - v;
    if (t < NBKT) { bbase[t] = excl; bcur[t] = excl; }
}

// ---------------- binning: group edges by bucket with LDS staging ----------------
__global__ __launch_bounds__(256) void bin_kernel(const int* __restrict__ src,
        const int* __restrict__ dst, int* __restrict__ bcur,
        unsigned int* __restrict__ ebin) {
    __shared__ unsigned int ebuf[CHUNK];        // 32 KB
    __shared__ unsigned short bids[CHUNK];      // 16 KB
    __shared__ int hist[NBKT], lbase[NBKT], lcur[NBKT], delta[NBKT];
    __shared__ int wsum4[4];
    __shared__ int carry;
    int t = threadIdx.x;
    int lane = t & 63, w = t >> 6;
    int c0 = blockIdx.x * CHUNK;
    int cnt = min(CHUNK, NE - c0);
    for (int i = t; i < NBKT; i += 256) hist[i] = 0;
    if (t == 0) carry = 0;
    __syncthreads();
    for (int i = t; i < cnt; i += 256) atomicAdd(&hist[dst[c0 + i] >> BKT_SH], 1);
    __syncthreads();
    // in-block exclusive scan of hist -> lbase, lcur
    for (int bb = 0; bb < NBKT; bb += 256) {
        int i = bb + t;
        int v = (i < NBKT) ? hist[i] : 0;
        int incl = v;
        #pragma unroll
        for (int d2 = 1; d2 < 64; d2 <<= 1) {
            int u = __shfl_up(incl, d2, 64);
            if (lane >= d2) incl += u;
        }
        if (lane == 63) wsum4[w] = incl;
        __syncthreads();
        int wo = 0;
        if (w > 0) wo = wsum4[0];
        if (w > 1) wo += wsum4[1];
        if (w > 2) wo += wsum4[2];
        int excl = carry + wo + incl - v;
        if (i < NBKT) { lbase[i] = excl; lcur[i] = excl; }
        int tot = wsum4[0] + wsum4[1] + wsum4[2] + wsum4[3];
        __syncthreads();
        if (t == 0) carry += tot;
        __syncthreads();
    }
    // reserve global runs: one atomic per (block,bucket)
    for (int b = t; b < NBKT; b += 256) {
        int hh = hist[b];
        delta[b] = (hh ? atomicAdd(&bcur[b], hh) : 0) - lbase[b];
    }
    __syncthreads();
    // scatter into LDS grouped by bucket
    for (int i = t; i < cnt; i += 256) {
        int d = dst[c0 + i];
        int s = src[c0 + i];
        int b = d >> BKT_SH;
        unsigned int entry = ((unsigned int)s << BKT_SH) | (unsigned int)(d & 127);
        int p = atomicAdd(&lcur[b], 1);
        ebuf[p] = entry;
        bids[p] = (unsigned short)b;
    }
    __syncthreads();
    // copy out: consecutive slots in same bucket -> consecutive global addresses
    for (int i = t; i < cnt; i += 256) {
        ebin[delta[bids[i]] + i] = ebuf[i];
    }
}

// ---------------- aggregation per bucket: out[i] = x[i] + sum_{j->i} x[j] ----------------
__global__ __launch_bounds__(256) void aggregate_bucket_kernel(const float* __restrict__ x,
        const int* __restrict__ bbase, const int* __restrict__ bcnt,
        const unsigned int* __restrict__ ebin, float* __restrict__ out) {
    __shared__ unsigned int ebuf[MAXB];     // 24 KB
    __shared__ unsigned int sorted[MAXB];   // 24 KB (src only)
    __shared__ int nh[128], nbase[129], ncur[128];
    int b = blockIdx.x, t = threadIdx.x;
    int base = bbase[b];
    int cnt = min(bcnt[b], MAXB);
    if (t < 128) nh[t] = 0;
    __syncthreads();
    for (int i = t; i < cnt; i += 256) {
        unsigned int e = ebin[base + i];
        ebuf[i] = e;
        atomicAdd(&nh[e & 127], 1);
    }
    __syncthreads();
    if (t < 64) {
        int v0 = nh[t], v1 = nh[64 + t];
        int i0 = v0;
        #pragma unroll
        for (int d = 1; d < 64; d <<= 1) {
            int u = __shfl_up(i0, d, 64);
            if (t >= d) i0 += u;
        }
        int tot0 = __shfl(i0, 63, 64);
        int i1 = v1;
        #pragma unroll
        for (int d = 1; d < 64; d <<= 1) {
            int u = __shfl_up(i1, d, 64);
            if (t >= d) i1 += u;
        }
        nbase[t] = i0 - v0;
        nbase[64 + t] = tot0 + i1 - v1;
        ncur[t] = i0 - v0;
        ncur[64 + t] = tot0 + i1 - v1;
        if (t == 63) nbase[128] = tot0 + i1;
    }
    __syncthreads();
    for (int i = t; i < cnt; i += 256) {
        unsigned int e = ebuf[i];
        int p = atomicAdd(&ncur[e & 127], 1);
        sorted[p] = e >> BKT_SH;
    }
    __syncthreads();
    int w = t >> 6, lane = t & 63;
    const float2* x2 = (const float2*)x;
    for (int j = 0; j < 32; ++j) {
        int ni = w + j * 4;                 // striped across waves for balance
        int node = b * 128 + ni;
        if (node >= NN) break;
        float2 acc = x2[(size_t)node * 64 + lane];
        int s = nbase[ni], e2 = nbase[ni + 1];
        int i = s;
        for (; i + 8 <= e2; i += 8) {
            int s0 = sorted[i + 0], s1 = sorted[i + 1], s2 = sorted[i + 2], s3 = sorted[i + 3];
            int s4 = sorted[i + 4], s5 = sorted[i + 5], s6 = sorted[i + 6], s7 = sorted[i + 7];
            float2 v0 = x2[(size_t)s0 * 64 + lane];
            float2 v1 = x2[(size_t)s1 * 64 + lane];
            float2 v2 = x2[(size_t)s2 * 64 + lane];
            float2 v3 = x2[(size_t)s3 * 64 + lane];
            float2 v4 = x2[(size_t)s4 * 64 + lane];
            float2 v5 = x2[(size_t)s5 * 64 + lane];
            float2 v6 = x2[(size_t)s6 * 64 + lane];
            float2 v7 = x2[(size_t)s7 * 64 + lane];
            acc.x += v0.x; acc.y += v0.y;
            acc.x += v1.x; acc.y += v1.y;
            acc.x += v2.x; acc.y += v2.y;
            acc.x += v3.x; acc.y += v3.y;
            acc.x += v4.x; acc.y += v4.y;
            acc.x += v5.x; acc.y += v5.y;
            acc.x += v6.x; acc.y += v6.y;
            acc.x += v7.x; acc.y += v7.y;
        }
        for (; i < e2; ++i) {
            int sv = sorted[i];
            float2 v = x2[(size_t)sv * 64 + lane];
            acc.x += v.x; acc.y += v.y;
        }
        ((float2*)out)[(size_t)node * 64 + lane] = acc;
    }
}

// ---------------- f32 GEMM: C = [relu](A[M,128] @ W[128,128] + b) ----------------
template<int RELU>
__global__ __launch_bounds__(256, 2) void gemm128_kernel(const float* __restrict__ A,
        const float* __restrict__ W, const float* __restrict__ bias,
        float* __restrict__ Cout, int M) {
    __shared__ float As[64][132];
    __shared__ float Ws[128][64];
    int t = threadIdx.x;
    int bm = blockIdx.x, bn = blockIdx.y;
    int row0 = bm * 64;
    {
        const float4* A4 = (const float4*)A;
        #pragma unroll
        for (int i = 0; i < 8; ++i) {
            int idx = i * 256 + t;
            int r = idx >> 5, c4 = idx & 31;
            int gr = row0 + r;
            float4 v = (gr < M) ? A4[(size_t)gr * 32 + c4] : make_float4(0.f, 0.f, 0.f, 0.f);
            *(float4*)&As[r][c4 * 4] = v;
        }
        const float4* W4 = (const float4*)W;
        #pragma unroll
        for (int i = 0; i < 8; ++i) {
            int idx = i * 256 + t;
            int k = idx >> 4, c4 = idx & 15;
            float4 v = W4[(size_t)k * 32 + bn * 16 + c4];
            *(float4*)&Ws[k][c4 * 4] = v;
        }
    }
    __syncthreads();
    int tc = t & 15, tr = t >> 4;
    int c0 = tc * 4;
    float acc[4][4] = {};
    for (int k = 0; k < 128; k += 4) {
        float4 a[4], w[4];
        #pragma unroll
        for (int j = 0; j < 4; ++j) a[j] = *(const float4*)&As[tr * 4 + j][k];
        #pragma unroll
        for (int kk = 0; kk < 4; ++kk) w[kk] = *(const float4*)&Ws[k + kk][c0];
        #pragma unroll
        for (int j = 0; j < 4; ++j) {
            float av[4] = {a[j].x, a[j].y, a[j].z, a[j].w};
            #pragma unroll
            for (int kk = 0; kk < 4; ++kk) {
                acc[j][0] += av[kk] * w[kk].x;
                acc[j][1] += av[kk] * w[kk].y;
                acc[j][2] += av[kk] * w[kk].z;
                acc[j][3] += av[kk] * w[kk].w;
            }
        }
    }
    float4 b4 = *(const float4*)&bias[bn * 64 + c0];
    #pragma unroll
    for (int j = 0; j < 4; ++j) {
        int gr = row0 + tr * 4 + j;
        if (gr < M) {
            float4 v = make_float4(acc[j][0] + b4.x, acc[j][1] + b4.y,
                                   acc[j][2] + b4.z, acc[j][3] + b4.w);
            if (RELU) {
                v.x = fmaxf(v.x, 0.f); v.y = fmaxf(v.y, 0.f);
                v.z = fmaxf(v.z, 0.f); v.w = fmaxf(v.w, 0.f);
            }
            *(float4*)&Cout[(size_t)gr * 128 + bn * 64 + c0] = v;
        }
    }
}

// ---------------- BN stats: per-channel sum & sumsq ----------------
__global__ void bn_stats_kernel(const float* __restrict__ U, float* __restrict__ stats) {
    int tid = blockIdx.x * 256 + threadIdx.x;
    int chn = tid & 127;
    float s = 0.f, sq = 0.f;
    const int total = NN * CH;
    for (int i = tid; i < total; i += 2048 * 256) {
        float v = U[i];
        s += v; sq += v * v;
    }
    atomicAdd(&stats[chn], s);
    atomicAdd(&stats[128 + chn], sq);
}

__global__ void bn_relu_kernel(const float* __restrict__ U, const float* __restrict__ stats,
        const float* __restrict__ gamma, const float* __restrict__ beta,
        float* __restrict__ out) {
    int tid = blockIdx.x * 256 + threadIdx.x;   // one float4 each; grid exact
    int c4 = tid & 31;
    float4 u  = ((const float4*)U)[tid];
    float4 sm = ((const float4*)stats)[c4];
    float4 sq = ((const float4*)(stats + 128))[c4];
    float4 g  = ((const float4*)gamma)[c4];
    float4 be = ((const float4*)beta)[c4];
    const float inv = 1.0f / NN;
    float4 o;
    {
        float mean = sm.x * inv, var = sq.x * inv - mean * mean;
        o.x = fmaxf((u.x - mean) * rsqrtf(var + BN_EPS) * g.x + be.x, 0.f);
    }
    {
        float mean = sm.y * inv, var = sq.y * inv - mean * mean;
        o.y = fmaxf((u.y - mean) * rsqrtf(var + BN_EPS) * g.y + be.y, 0.f);
    }
    {
        float mean = sm.z * inv, var = sq.z * inv - mean * mean;
        o.z = fmaxf((u.z - mean) * rsqrtf(var + BN_EPS) * g.z + be.z, 0.f);
    }
    {
        float mean = sm.w * inv, var = sq.w * inv - mean * mean;
        o.w = fmaxf((u.w - mean) * rsqrtf(var + BN_EPS) * g.w + be.w, 0.f);
    }
    ((float4*)out)[tid] = o;
}

// ---------------- pooling: segment_sum over sorted batch ----------------
__global__ void pool_kernel(const float* __restrict__ h, const int* __restrict__ batch,
                            float* __restrict__ pooled) {
    int g = blockIdx.x;
    int t = threadIdx.x;   // 128
    int a = 0, b = NN;
    while (a < b) { int m = (a + b) >> 1; if (batch[m] < g) a = m + 1; else b = m; }
    int start = a;
    b = NN;
    while (a < b) { int m = (a + b) >> 1; if (batch[m] < g + 1) a = m + 1; else b = m; }
    int end = a;
    float s = 0.f;
    for (int i = start; i < end; ++i) s += h[(size_t)i * 128 + t];
    pooled[g * 128 + t] = s;
}

// ---------------- head: logits + log_softmax ----------------
__global__ void head_kernel(const float* __restrict__ pooled, const float* __restrict__ Wlin,
                            const float* __restrict__ blin, float* __restrict__ out) {
    int g = blockIdx.x;
    int lane = threadIdx.x;  // 64
    float2 p = ((const float2*)pooled)[g * 64 + lane];
    float l[10];
    #pragma unroll
    for (int o = 0; o < 10; ++o) {
        float partial = p.x * Wlin[(2 * lane) * 10 + o] + p.y * Wlin[(2 * lane + 1) * 10 + o];
        #pragma unroll
        for (int m = 1; m < 64; m <<= 1) partial += __shfl_xor(partial, m, 64);
        l[o] = partial + blin[o];
    }
    float mx = l[0];
    #pragma unroll
    for (int o = 1; o < 10; ++o) mx = fmaxf(mx, l[o]);
    float se = 0.f;
    #pragma unroll
    for (int o = 0; o < 10; ++o) se += expf(l[o] - mx);
    float lse = mx + logf(se);
    if (lane == 0) {
        #pragma unroll
        for (int o = 0; o < 10; ++o) out[g * 10 + o] = l[o] - lse;
    }
}

extern "C" void kernel_launch(void* const* d_in, const int* in_sizes, int n_in,
                              void* d_out, int out_size, void* d_ws, size_t ws_size,
                              hipStream_t stream) {
    const float* x    = (const float*)d_in[0];
    const int*   edge = (const int*)d_in[1];   // [2][NE]
    const int*   batch= (const int*)d_in[2];
    const float* W1a  = (const float*)d_in[3];
    const float* b1a  = (const float*)d_in[4];
    const float* W1b  = (const float*)d_in[5];
    const float* b1b  = (const float*)d_in[6];
    const float* g1   = (const float*)d_in[7];
    const float* be1  = (const float*)d_in[8];
    const float* W2a  = (const float*)d_in[9];
    const float* b2a  = (const float*)d_in[10];
    const float* W2b  = (const float*)d_in[11];
    const float* b2b  = (const float*)d_in[12];
    const float* g2   = (const float*)d_in[13];
    const float* be2  = (const float*)d_in[14];
    const float* Wlin = (const float*)d_in[15];
    const float* blin = (const float*)d_in[16];
    float* out = (float*)d_out;

    char* ws = (char*)d_ws;
    size_t off = 0;
    auto alloc = [&](size_t bytes) -> void* {
        void* p = ws + off; off += (bytes + 255) & ~(size_t)255; return p;
    };
    float* bufA   = (float*)alloc((size_t)NN * CH * 4);
    float* bufB   = (float*)alloc((size_t)NN * CH * 4);
    unsigned int* ebin = (unsigned int*)alloc((size_t)NE * 4);
    int*   bcnt   = (int*)alloc(NBKT * 4);
    int*   bbase  = (int*)alloc(NBKT * 4);
    int*   bcur   = (int*)alloc(NBKT * 4);
    float* stats1 = (float*)alloc(256 * 4);
    float* stats2 = (float*)alloc(256 * 4);
    float* pooled = (float*)alloc(NG * CH * 4);

    const int* srcI = edge;
    const int* dstI = edge + NE;

    hipMemsetAsync(bcnt, 0, NBKT * 4, stream);
    hipMemsetAsync(stats1, 0, 256 * 4, stream);
    hipMemsetAsync(stats2, 0, 256 * 4, stream);

    bucket_count_kernel<<<NBINBLK, 256, 0, stream>>>(dstI, bcnt);
    bucket_scan_kernel<<<1, 1024, 0, stream>>>(bcnt, bbase, bcur);
    bin_kernel<<<NBINBLK, 256, 0, stream>>>(srcI, dstI, bcur, ebin);

    dim3 ggrid(1563, 2);
    // ---- layer 1 ----
    aggregate_bucket_kernel<<<NBKT, 256, 0, stream>>>(x, bbase, bcnt, ebin, bufA);
    gemm128_kernel<1><<<ggrid, 256, 0, stream>>>(bufA, W1a, b1a, bufB, NN);
    gemm128_kernel<0><<<ggrid, 256, 0, stream>>>(bufB, W1b, b1b, bufA, NN);
    bn_stats_kernel<<<2048, 256, 0, stream>>>(bufA, stats1);
    bn_relu_kernel<<<12500, 256, 0, stream>>>(bufA, stats1, g1, be1, bufA);
    // ---- layer 2 ----
    aggregate_bucket_kernel<<<NBKT, 256, 0, stream>>>(bufA, bbase, bcnt, ebin, bufB);
    gemm128_kernel<1><<<ggrid, 256, 0, stream>>>(bufB, W2a, b2a, bufA, NN);
    gemm128_kernel<0><<<ggrid, 256, 0, stream>>>(bufA, W2b, b2b, bufB, NN);
    bn_stats_kernel<<<2048, 256, 0, stream>>>(bufB, stats2);
    bn_relu_kernel<<<12500, 256, 0, stream>>>(bufB, stats2, g2, be2, bufB);

    pool_kernel<<<NG, 128, 0, stream>>>(bufB, batch, pooled);
    head_kernel<<<NG, 64, 0, stream>>>(pooled, Wlin, blin, out);
}